// Round 12
// baseline (276.219 us; speedup 1.0000x reference)
//
#include <hip/hip_runtime.h>
#include <math.h>

#define SILU_SCALE 1.8137993642342178f   // pi/sqrt(3)
#define QKV_N 9216                       // 4096 Q | 1024 K | 4096 V
#define LN2 0.6931471805599453f
#define DNSCALE 0.18033688011112042f     // 0.125 * log2(e)

typedef __attribute__((ext_vector_type(8))) short bf16x8;
typedef __attribute__((ext_vector_type(4))) float f32x4;

#if __has_builtin(__builtin_amdgcn_exp2f)
#define EXP2(x) __builtin_amdgcn_exp2f(x)
#else
#define EXP2(x) exp2f(x)
#endif
#if __has_builtin(__builtin_amdgcn_logf)
#define LOG2(x) __builtin_amdgcn_logf(x)
#else
#define LOG2(x) __log2f(x)
#endif

__device__ __forceinline__ unsigned short f2bf(float f){
    union { float f; unsigned int i; } u; u.f = f;
    unsigned int r = u.i + 0x7FFFu + ((u.i >> 16) & 1u);   // RNE
    return (unsigned short)(r >> 16);
}
__device__ __forceinline__ float bf2f(unsigned short s){
    union { unsigned int i; float f; } u; u.i = ((unsigned int)s) << 16;
    return u.f;
}
// pack two fp32 -> [hi:lo] bf16 pair
__device__ __forceinline__ unsigned int pack_bf2(float lo, float hi){
    unsigned int i0 = __float_as_uint(lo) + 0x8000u;
    unsigned int i1 = __float_as_uint(hi) + 0x8000u;
    return __builtin_amdgcn_perm(i1, i0, 0x07060302u);
}
#if __has_builtin(__builtin_amdgcn_cvt_pk_bf16_f32)
typedef __attribute__((ext_vector_type(2))) __bf16 bfp2;
__device__ __forceinline__ unsigned int pack_bf2f(float lo, float hi){
    bfp2 t = __builtin_amdgcn_cvt_pk_bf16_f32(lo, hi);
    return __builtin_bit_cast(unsigned int, t);
}
#else
__device__ __forceinline__ unsigned int pack_bf2f(float lo, float hi){
    return pack_bf2(lo, hi);
}
#endif

// ---------------- fused prep: 4 weight transposes (64x64 tiles) + X convert + bias ----------------
__global__ __launch_bounds__(256) void prep_kernel(
    const float* __restrict__ X,
    const float* __restrict__ Wq, const float* __restrict__ Wk,
    const float* __restrict__ Wv, const float* __restrict__ Wo,
    const float* __restrict__ bq, const float* __restrict__ bk,
    const float* __restrict__ bv,
    unsigned short* __restrict__ Xb, unsigned short* __restrict__ WqkvT,
    unsigned short* __restrict__ WoT, float* __restrict__ qkvb)
{
    __shared__ float t[64][65];
    int b = blockIdx.x;
    const int tid = threadIdx.x;

    if (b >= 2560){
        if (b < 3072){   // X fp32 -> bf16, 8/thread
            int i = ((b - 2560) * 256 + tid) * 8;
            float4 a = *(const float4*)&X[i];
            float4 c = *(const float4*)&X[i + 4];
            union { unsigned short u[8]; uint4 v; } o;
            o.u[0]=f2bf(a.x); o.u[1]=f2bf(a.y); o.u[2]=f2bf(a.z); o.u[3]=f2bf(a.w);
            o.u[4]=f2bf(c.x); o.u[5]=f2bf(c.y); o.u[6]=f2bf(c.z); o.u[7]=f2bf(c.w);
            *(uint4*)&Xb[i] = o.v;
        } else {          // bias pack
            int i = (b - 3072) * 256 + tid;
            float v;
            if (i < 4096) v = bq[i];
            else if (i < 5120) v = bk[i - 4096];
            else v = bv[i - 5120];
            qkvb[i] = v;
        }
        return;
    }

    const float* W; unsigned short* Wt; int N, tiles_x;
    if (b < 1024)      { W = Wq; Wt = WqkvT;                       N = 4096; tiles_x = 64; }
    else if (b < 1280) { b -= 1024; W = Wk; Wt = WqkvT + (size_t)4096*1024; N = 1024; tiles_x = 16; }
    else if (b < 2304) { b -= 1280; W = Wv; Wt = WqkvT + (size_t)5120*1024; N = 4096; tiles_x = 64; }
    else               { b -= 2304; W = Wo; Wt = WoT;              N = 1024; tiles_x = 16; }

    const int k0 = (b / tiles_x) * 64, n0 = (b % tiles_x) * 64;
    const int lr  = tid >> 4;          // 0..15
    const int lc4 = (tid & 15) * 4;    // 0..60
    #pragma unroll
    for (int p = 0; p < 4; p++){
        int r = lr + p * 16;
        float4 v = *(const float4*)&W[(size_t)(k0 + r) * N + n0 + lc4];
        t[lc4+0][r] = v.x; t[lc4+1][r] = v.y;
        t[lc4+2][r] = v.z; t[lc4+3][r] = v.w;
    }
    __syncthreads();
    const int wr  = tid >> 3;          // 0..31
    const int wc8 = (tid & 7) * 8;     // 0..56
    #pragma unroll
    for (int p = 0; p < 2; p++){
        int r = wr + p * 32;
        union { unsigned short u[8]; uint4 v; } o;
        #pragma unroll
        for (int j = 0; j < 8; j++) o.u[j] = f2bf(t[r][wc8 + j]);
        *(uint4*)&Wt[(size_t)(n0 + r) * 1024 + k0 + wc8] = o.v;
    }
}

// ---- bf16 MFMA GEMM, register-prefetch pipelined: C = A[M,K] @ Bt[N,K]^T + bias ----
// __launch_bounds__(256, 2): VGPR budget 128 — fits acc(48)+prefetch(28)+frags(28)+addr
// without scratch spill (r11 default budget was 76 -> 195MB spill traffic).
template<int BM, int BN, int OUTBF>
__global__ __launch_bounds__(256, 2) void gemm_k(
    const unsigned short* __restrict__ A,
    const unsigned short* __restrict__ Bt,
    const float* __restrict__ bias,
    void* __restrict__ Cout, int M, int N, int K)
{
    constexpr int MT = BM / 32;
    constexpr int NT = BN / 32;
    constexpr int ASL = (BM * 8) / 256;   // A uint4 slots per thread
    constexpr int BSL = (BN * 8) / 256;   // B uint4 slots per thread
    __shared__ unsigned short As[BM * 64];
    __shared__ unsigned short Bs[BN * 64];
    const int tid  = threadIdx.x;
    const int wave = tid >> 6;
    const int lane = tid & 63;
    const int l15  = lane & 15;
    const int quad = lane >> 4;
    const int m0 = blockIdx.y * BM;
    const int n0 = blockIdx.x * BN;
    const int wm = (wave >> 1) * (BM / 2);
    const int wn = (wave & 1) * (BN / 2);

    int arow[ASL], acol[ASL], brow[BSL], bcol[BSL];
    #pragma unroll
    for (int i = 0; i < ASL; i++){
        int slot = i * 256 + tid;
        arow[i] = slot >> 3;
        acol[i] = (slot & 7) ^ (arow[i] & 7);
    }
    #pragma unroll
    for (int i = 0; i < BSL; i++){
        int slot = i * 256 + tid;
        brow[i] = slot >> 3;
        bcol[i] = (slot & 7) ^ (brow[i] & 7);
    }

    f32x4 acc[MT][NT];
    #pragma unroll
    for (int i = 0; i < MT; i++)
        #pragma unroll
        for (int j = 0; j < NT; j++)
            acc[i][j] = (f32x4){0.f, 0.f, 0.f, 0.f};

    uint4 ar[ASL], br[BSL];
    #pragma unroll
    for (int i = 0; i < ASL; i++)
        ar[i] = *(const uint4*)&A[(size_t)(m0 + arow[i]) * K + acol[i] * 8];
    #pragma unroll
    for (int i = 0; i < BSL; i++)
        br[i] = *(const uint4*)&Bt[(size_t)(n0 + brow[i]) * K + bcol[i] * 8];

    for (int k0 = 0; k0 < K; k0 += 64){
        __syncthreads();                 // previous tile's LDS reads done
        #pragma unroll
        for (int i = 0; i < ASL; i++)
            *(uint4*)&As[(size_t)(i * 256 + tid) * 8] = ar[i];
        #pragma unroll
        for (int i = 0; i < BSL; i++)
            *(uint4*)&Bs[(size_t)(i * 256 + tid) * 8] = br[i];

        if (k0 + 64 < K){                // prefetch next K-tile under this tile's MFMA
            #pragma unroll
            for (int i = 0; i < ASL; i++)
                ar[i] = *(const uint4*)&A[(size_t)(m0 + arow[i]) * K + k0 + 64 + acol[i] * 8];
            #pragma unroll
            for (int i = 0; i < BSL; i++)
                br[i] = *(const uint4*)&Bt[(size_t)(n0 + brow[i]) * K + k0 + 64 + bcol[i] * 8];
        }
        __syncthreads();                 // staging visible

        #pragma unroll
        for (int ks = 0; ks < 2; ks++){
            bf16x8 af[MT], bfr[NT];
            #pragma unroll
            for (int i = 0; i < MT; i++){
                int row = wm + i * 16 + l15;
                int phys = (ks * 4 + quad) ^ (row & 7);
                af[i] = *(const bf16x8*)&As[row * 64 + phys * 8];
            }
            #pragma unroll
            for (int j = 0; j < NT; j++){
                int row = wn + j * 16 + l15;
                int phys = (ks * 4 + quad) ^ (row & 7);
                bfr[j] = *(const bf16x8*)&Bs[row * 64 + phys * 8];
            }
            #pragma unroll
            for (int i = 0; i < MT; i++)
                #pragma unroll
                for (int j = 0; j < NT; j++)
                    acc[i][j] = __builtin_amdgcn_mfma_f32_16x16x32_bf16(af[i], bfr[j], acc[i][j], 0, 0, 0);
        }
    }
    #pragma unroll
    for (int i = 0; i < MT; i++){
        #pragma unroll
        for (int j = 0; j < NT; j++){
            int col = n0 + wn + j * 16 + l15;
            float bv = bias[col];
            #pragma unroll
            for (int r = 0; r < 4; r++){
                int row = m0 + wm + i * 16 + quad * 4 + r;
                float v = acc[i][j][r] + bv;
                if (OUTBF) ((unsigned short*)Cout)[(size_t)row * N + col] = f2bf(v);
                else       ((float*)Cout)[(size_t)row * N + col] = v;
            }
        }
    }
}

// ---------------- Wo GEMM, split-K=2, register-prefetch pipelined ----------------
__global__ __launch_bounds__(256, 2) void gemm_wo(
    const unsigned short* __restrict__ A,    // avgb [1024][1024] bf16
    const unsigned short* __restrict__ Bt,   // WoT  [1024][1024] bf16
    float* __restrict__ P)                   // [2][1024][1024] fp32 partials
{
    constexpr int BM = 128, BN = 64, MT = 4, NT = 2;
    constexpr int ASL = 4, BSL = 2;
    __shared__ unsigned short As[BM * 64];
    __shared__ unsigned short Bs[BN * 64];
    const int tid  = threadIdx.x;
    const int wave = tid >> 6;
    const int lane = tid & 63;
    const int l15  = lane & 15;
    const int quad = lane >> 4;
    const int m0 = blockIdx.y * BM;
    const int n0 = blockIdx.x * BN;
    const int kz = blockIdx.z;
    const int wm = (wave >> 1) * 64;
    const int wn = (wave & 1) * 32;

    int arow[ASL], acol[ASL], brow[BSL], bcol[BSL];
    #pragma unroll
    for (int i = 0; i < ASL; i++){
        int slot = i * 256 + tid;
        arow[i] = slot >> 3;
        acol[i] = (slot & 7) ^ (arow[i] & 7);
    }
    #pragma unroll
    for (int i = 0; i < BSL; i++){
        int slot = i * 256 + tid;
        brow[i] = slot >> 3;
        bcol[i] = (slot & 7) ^ (brow[i] & 7);
    }

    f32x4 acc[MT][NT];
    #pragma unroll
    for (int i = 0; i < MT; i++)
        #pragma unroll
        for (int j = 0; j < NT; j++)
            acc[i][j] = (f32x4){0.f, 0.f, 0.f, 0.f};

    const int kbeg = kz * 512;
    uint4 ar[ASL], br[BSL];
    #pragma unroll
    for (int i = 0; i < ASL; i++)
        ar[i] = *(const uint4*)&A[(size_t)(m0 + arow[i]) * 1024 + kbeg + acol[i] * 8];
    #pragma unroll
    for (int i = 0; i < BSL; i++)
        br[i] = *(const uint4*)&Bt[(size_t)(n0 + brow[i]) * 1024 + kbeg + bcol[i] * 8];

    for (int k0 = kbeg; k0 < kbeg + 512; k0 += 64){
        __syncthreads();
        #pragma unroll
        for (int i = 0; i < ASL; i++)
            *(uint4*)&As[(size_t)(i * 256 + tid) * 8] = ar[i];
        #pragma unroll
        for (int i = 0; i < BSL; i++)
            *(uint4*)&Bs[(size_t)(i * 256 + tid) * 8] = br[i];

        if (k0 + 64 < kbeg + 512){
            #pragma unroll
            for (int i = 0; i < ASL; i++)
                ar[i] = *(const uint4*)&A[(size_t)(m0 + arow[i]) * 1024 + k0 + 64 + acol[i] * 8];
            #pragma unroll
            for (int i = 0; i < BSL; i++)
                br[i] = *(const uint4*)&Bt[(size_t)(n0 + brow[i]) * 1024 + k0 + 64 + bcol[i] * 8];
        }
        __syncthreads();

        #pragma unroll
        for (int ks = 0; ks < 2; ks++){
            bf16x8 af[MT], bfr[NT];
            #pragma unroll
            for (int i = 0; i < MT; i++){
                int row = wm + i * 16 + l15;
                int phys = (ks * 4 + quad) ^ (row & 7);
                af[i] = *(const bf16x8*)&As[row * 64 + phys * 8];
            }
            #pragma unroll
            for (int j = 0; j < NT; j++){
                int row = wn + j * 16 + l15;
                int phys = (ks * 4 + quad) ^ (row & 7);
                bfr[j] = *(const bf16x8*)&Bs[row * 64 + phys * 8];
            }
            #pragma unroll
            for (int i = 0; i < MT; i++)
                #pragma unroll
                for (int j = 0; j < NT; j++)
                    acc[i][j] = __builtin_amdgcn_mfma_f32_16x16x32_bf16(af[i], bfr[j], acc[i][j], 0, 0, 0);
        }
    }
    float* Pz = P + (size_t)kz * 1024 * 1024;
    #pragma unroll
    for (int i = 0; i < MT; i++){
        #pragma unroll
        for (int j = 0; j < NT; j++){
            int col = n0 + wn + j * 16 + l15;
            #pragma unroll
            for (int r = 0; r < 4; r++){
                int row = m0 + wm + i * 16 + quad * 4 + r;
                Pz[(size_t)row * 1024 + col] = acc[i][j][r];
            }
        }
    }
}

// out = P[0] + P[1] + bias  (fp32, 4/thread)
__global__ void wo_reduce(const float* __restrict__ P, const float* __restrict__ bo,
                          float* __restrict__ out)
{
    int i = (blockIdx.x * 256 + threadIdx.x) * 4;   // 1M floats
    float4 a = *(const float4*)&P[i];
    float4 b = *(const float4*)&P[1024 * 1024 + i];
    float4 c = *(const float4*)&bo[i & 1023];
    float4 o;
    o.x = a.x + b.x + c.x; o.y = a.y + b.y + c.y;
    o.z = a.z + b.z + c.z; o.w = a.w + b.w + c.w;
    *(float4*)&out[i] = o;
}

// ---------------- postproc: K-rope + fold 0.125*log2e/||k|| INTO K; V pre-transpose ----------------
__global__ __launch_bounds__(256) void postproc_kernel(
    unsigned short* __restrict__ qkv, unsigned short* __restrict__ VT)
{
    int b = blockIdx.x;
    const int tid = threadIdx.x;
    if (b < 64){
        int idx = b * 256 + tid;     // 16384: (t, kh 0..15)
        int t = idx >> 4, h = idx & 15;
        unsigned short* p = qkv + (size_t)t * QKV_N + 4096 + h * 64;
        uint4 raw[8];
        #pragma unroll
        for (int i = 0; i < 8; i++) raw[i] = *(const uint4*)(p + i * 8);
        const unsigned short* rp = (const unsigned short*)raw;
        float x[64];
        #pragma unroll
        for (int i = 0; i < 64; i++) x[i] = bf2f(rp[i]);
        float ra[32], rb[32];
        float ss = 0.f;
        #pragma unroll
        for (int d = 0; d < 32; d++){
            float inv = EXP2(-(float)d * 0.4152410118609203f);   // log2(1e4)/32
            float s, c; __sincosf((float)t * inv, &s, &c);
            float x1 = x[2*d], x2 = x[2*d+1];
            float a = x1 * c - x2 * s;
            float bb = x1 * s + x2 * c;
            ss = fmaf(a, a, fmaf(bb, bb, ss));
            ra[d] = a; rb[d] = bb;
        }
        // fold the score scale into K: K' = roped_K * 0.125*log2e/||k||
        float scale = DNSCALE * rsqrtf(fmaxf(ss, 1e-6f));
        unsigned short o[64];
        #pragma unroll
        for (int d = 0; d < 32; d++){
            o[d]      = f2bf(ra[d] * scale);
            o[d + 32] = f2bf(rb[d] * scale);
        }
        #pragma unroll
        for (int i = 0; i < 8; i++) *(uint4*)(p + i * 8) = ((const uint4*)o)[i];
        return;
    }
    // V transpose: tile (h, tb): V[s0..+64][h*64..+64] -> VT[h][d][s0..+64]
    b -= 64;
    const int h = b >> 4, s0 = (b & 15) * 64;
    __shared__ unsigned short tile[64 * 64];
    const unsigned short* V = qkv + 5120;
    const int pr = tid >> 3, cch = tid & 7;
    uint4 g0 = *(const uint4*)&V[(size_t)(s0 + 2 * pr)     * QKV_N + h * 64 + cch * 8];
    uint4 g1 = *(const uint4*)&V[(size_t)(s0 + 2 * pr + 1) * QKV_N + h * 64 + cch * 8];
    const unsigned short* p0 = (const unsigned short*)&g0;
    const unsigned short* p1 = (const unsigned short*)&g1;
    #pragma unroll
    for (int j = 0; j < 8; j++){
        int d = cch * 8 + j;
        int physc = (pr >> 2) ^ ((d ^ (d >> 3)) & 7);
        unsigned int val = (unsigned int)p0[j] | ((unsigned int)p1[j] << 16);
        ((unsigned int*)tile)[d * 32 + physc * 4 + (pr & 3)] = val;
    }
    __syncthreads();
    #pragma unroll
    for (int i = 0; i < 2; i++){
        int slot = tid + i * 256;
        int d = slot >> 3, c = slot & 7;
        int phys = c ^ ((d ^ (d >> 3)) & 7);
        uint4 v = *(const uint4*)&tile[d * 64 + phys * 8];
        *(uint4*)&VT[((size_t)h * 64 + d) * 1024 + s0 + c * 8] = v;
    }
}

// ---------------- fused attention (pipelined; K pre-scaled; den via MFMA-ones) ----------------
// grid (h 0..63, qy 0..15), qt = 15 - qy. 256 thr = 4 waves; wave w owns q rows [w*16,+16).
// P stores w/ln2; epilogue applies LN2 to num and den.
__global__ __launch_bounds__(256) void attn_mfma(
    const unsigned short* __restrict__ qkv,
    const unsigned short* __restrict__ VT,   // [64][64][1024]
    const float* __restrict__ sinks, const float* __restrict__ vnulls,
    unsigned short* __restrict__ ctx)        // [64][1024][64] bf16
{
    __shared__ unsigned short ks[64 * 64];   // [s][chunk ^ (s&7)]
    __shared__ unsigned short vt[64 * 64];   // [d][chunk ^ (d&7)]
    __shared__ unsigned short ws[64][72];    // P [q][s]

    const int tid  = threadIdx.x;
    const int wave = tid >> 6;          // 0..3
    const int lane = tid & 63;
    const int l15  = lane & 15;
    const int quad = lane >> 4;
    const int h  = blockIdx.x;
    const int kh = h & 15;
    const int qt = 15 - blockIdx.y;
    const int t0 = qt << 6;

    const unsigned short* Q  = qkv;
    const unsigned short* Kp = qkv + 4096;
    const unsigned short* Vh = VT + (size_t)h * 64 * 1024;

    const int srow0 = tid >> 3,         sphy0 = tid & 7;
    const int srow1 = (tid + 256) >> 3, sphy1 = tid & 7;
    const int sc0 = sphy0 ^ (srow0 & 7);
    const int sc1 = sphy1 ^ (srow1 & 7);

    // Q fragment with fused RoPE (Q in global is un-roped).
    bf16x8 qf0, qf1;
    {
        const int t = t0 + wave * 16 + l15;
        const unsigned short* qp = Q + (size_t)t * QKV_N + h * 64 + quad * 16;
        uint4 r0 = *(const uint4*)qp;
        uint4 r1 = *(const uint4*)(qp + 8);
        unsigned short e[16];
        *(uint4*)&e[0] = r0; *(uint4*)&e[8] = r1;
        unsigned short o0[8], o1[8];
        #pragma unroll
        for (int j = 0; j < 8; j++){
            int dp = quad * 8 + j;
            float inv = EXP2(-(float)dp * 0.4152410118609203f);
            float s, c; __sincosf((float)t * inv, &s, &c);
            float x1 = bf2f(e[2*j]), x2 = bf2f(e[2*j+1]);
            o0[j] = f2bf(x1 * c - x2 * s);
            o1[j] = f2bf(x1 * s + x2 * c);
        }
        qf0 = *(const bf16x8*)o0;
        qf1 = *(const bf16x8*)o1;
    }

    // ones fragment for the den row-sum MFMA
    bf16x8 ones;
    {
        union { unsigned short u[8]; bf16x8 v; } o;
        #pragma unroll
        for (int j = 0; j < 8; j++) o.u[j] = 0x3F80;   // bf16 1.0
        ones = o.v;
    }

    f32x4 acc_o[4];
    #pragma unroll
    for (int i = 0; i < 4; i++) acc_o[i] = (f32x4){0.f, 0.f, 0.f, 0.f};
    f32x4 acc_den = (f32x4){0.f, 0.f, 0.f, 0.f};   // den[q=quad*4+r] (cols duplicate)
    const int q_glob = t0 + wave * 16 + l15;

    uint4 kr0, kr1, vr0, vr1;
    // prefetch st = 0
    {
        kr0 = *(const uint4*)&Kp[(size_t)srow0 * QKV_N + kh * 64 + sc0 * 8];
        kr1 = *(const uint4*)&Kp[(size_t)srow1 * QKV_N + kh * 64 + sc1 * 8];
        vr0 = *(const uint4*)&Vh[(size_t)srow0 * 1024 + sc0 * 8];
        vr1 = *(const uint4*)&Vh[(size_t)srow1 * 1024 + sc1 * 8];
    }

    for (int st = 0; st <= qt; st++){
        const int s0 = st << 6;
        __syncthreads();                // previous iteration's LDS reads done

        *(uint4*)&ks[(size_t)tid * 8]         = kr0;
        *(uint4*)&ks[(size_t)(tid + 256) * 8] = kr1;
        *(uint4*)&vt[(size_t)tid * 8]         = vr0;
        *(uint4*)&vt[(size_t)(tid + 256) * 8] = vr1;

        if (st < qt){                   // prefetch next (latency hidden)
            const int sn = (st + 1) << 6;
            kr0 = *(const uint4*)&Kp[(size_t)(sn + srow0) * QKV_N + kh * 64 + sc0 * 8];
            kr1 = *(const uint4*)&Kp[(size_t)(sn + srow1) * QKV_N + kh * 64 + sc1 * 8];
            vr0 = *(const uint4*)&Vh[(size_t)srow0 * 1024 + sn + sc0 * 8];
            vr1 = *(const uint4*)&Vh[(size_t)srow1 * 1024 + sn + sc1 * 8];
        }
        __syncthreads();                // staging visible

        const bool diag = (st == qt);

        // S^T: mfma(kf, qf) -> lane owns 4 consecutive s (quad*4+r) for q = l15.
        // K is pre-scaled: y = sc directly (in log2 space). P' = w/ln2.
        #pragma unroll
        for (int nt = 0; nt < 4; nt++){
            const int sbase = nt * 16 + quad * 4;
            uint2* wp = (uint2*)&ws[wave * 16 + l15][sbase];
            if (diag && nt > wave){ *wp = (uint2){0u, 0u}; continue; }

            f32x4 sc = (f32x4){0.f, 0.f, 0.f, 0.f};
            {
                int srow = nt * 16 + l15;
                int ph0 = quad ^ (srow & 7);
                int ph1 = (4 + quad) ^ (srow & 7);
                bf16x8 kf0 = *(const bf16x8*)&ks[srow * 64 + ph0 * 8];
                bf16x8 kf1 = *(const bf16x8*)&ks[srow * 64 + ph1 * 8];
                sc = __builtin_amdgcn_mfma_f32_16x16x32_bf16(kf0, qf0, sc, 0, 0, 0);
                sc = __builtin_amdgcn_mfma_f32_16x16x32_bf16(kf1, qf1, sc, 0, 0, 0);
            }
            float w4[4];
            if (!diag){                 // fast path: no masking
                #pragma unroll
                for (int r = 0; r < 4; r++){
                    float y = sc[r];
                    float p = EXP2(-fabsf(y));
                    float u = fmaxf(y, 0.f) + LOG2(1.f + p);      // softplus * log2(e)
                    float e3 = EXP2(-SILU_SCALE * u);
                    w4[r] = __fdividef(u, 1.f + e3);              // w / ln2
                }
            } else {
                #pragma unroll
                for (int r = 0; r < 4; r++){
                    float y = sc[r];
                    float p = EXP2(-fabsf(y));
                    float u = fmaxf(y, 0.f) + LOG2(1.f + p);
                    float e3 = EXP2(-SILU_SCALE * u);
                    float wv = __fdividef(u, 1.f + e3);
                    w4[r] = (s0 + sbase + r <= q_glob) ? wv : 0.f;
                }
            }
            uint2 pk;
            pk.x = pack_bf2f(w4[0], w4[1]);
            pk.y = pack_bf2f(w4[2], w4[3]);
            *wp = pk;
        }

        // PV + den row-sum (wave-private ws rows)
        {
            const int prow = wave * 16 + l15;
            bf16x8 pf0 = *(const bf16x8*)&ws[prow][quad * 8];
            bf16x8 pf1 = *(const bf16x8*)&ws[prow][32 + quad * 8];
            const bool skip_hi = diag && (wave <= 1);   // s>=32 all masked (zeros)
            #pragma unroll
            for (int dt = 0; dt < 4; dt++){
                int d = dt * 16 + l15;
                int sw = d & 7;
                bf16x8 vf0 = *(const bf16x8*)&vt[d * 64 + (quad ^ sw) * 8];
                acc_o[dt] = __builtin_amdgcn_mfma_f32_16x16x32_bf16(pf0, vf0, acc_o[dt], 0, 0, 0);
                if (!skip_hi){
                    bf16x8 vf1 = *(const bf16x8*)&vt[d * 64 + ((4 + quad) ^ sw) * 8];
                    acc_o[dt] = __builtin_amdgcn_mfma_f32_16x16x32_bf16(pf1, vf1, acc_o[dt], 0, 0, 0);
                }
            }
            acc_den = __builtin_amdgcn_mfma_f32_16x16x32_bf16(pf0, ones, acc_den, 0, 0, 0);
            if (!skip_hi)
                acc_den = __builtin_amdgcn_mfma_f32_16x16x32_bf16(pf1, ones, acc_den, 0, 0, 0);
        }
    }

    // epilogue: den[q=quad*4+r] = acc_den[r]; apply LN2 scale to num and den
    float sinkv = tanhf(sinks[h]) + 1e-6f;
    #pragma unroll
    for (int r = 0; r < 4; r++){
        int qg = t0 + wave * 16 + quad * 4 + r;
        float alpha = __fdividef(1.f, LN2 * acc_den[r] + sinkv + 1e-6f);
        #pragma unroll
        for (int dt = 0; dt < 4; dt++){
            int d = dt * 16 + l15;
            float o = (LN2 * acc_o[dt][r] + sinkv * vnulls[h * 64 + d]) * alpha;
            ctx[((size_t)h * 1024 + qg) * 64 + d] = f2bf(o);
        }
    }
}

// avg over 4 branches -> bf16 [t][nh*64+d], 8 elems/thread
__global__ void avg_kernel(const unsigned short* __restrict__ ctx, unsigned short* __restrict__ avg)
{
    int i8 = (blockIdx.x * 256 + threadIdx.x) * 8;   // 1M elements
    int t = i8 >> 10, c = i8 & 1023;
    int nh = c >> 6, d = c & 63;
    float s[8] = {};
    #pragma unroll
    for (int br = 0; br < 4; br++){
        uint4 v = *(const uint4*)&ctx[((size_t)(br * 16 + nh) * 1024 + t) * 64 + d];
        const unsigned short* p = (const unsigned short*)&v;
        #pragma unroll
        for (int j = 0; j < 8; j++) s[j] += bf2f(p[j]);
    }
    union { unsigned short u[8]; uint4 v; } o;
    #pragma unroll
    for (int j = 0; j < 8; j++) o.u[j] = f2bf(0.25f * s[j]);
    *(uint4*)&avg[i8] = o.v;
}

extern "C" void kernel_launch(void* const* d_in, const int* in_sizes, int n_in,
                              void* d_out, int out_size, void* d_ws, size_t ws_size,
                              hipStream_t stream)
{
    (void)in_sizes; (void)n_in; (void)out_size; (void)ws_size;
    const float* X      = (const float*)d_in[0];
    const float* Wq     = (const float*)d_in[1];
    const float* bq     = (const float*)d_in[2];
    const float* Wk     = (const float*)d_in[3];
    const float* bk     = (const float*)d_in[4];
    const float* Wv     = (const float*)d_in[5];
    const float* bv     = (const float*)d_in[6];
    const float* sinks  = (const float*)d_in[7];
    const float* vnulls = (const float*)d_in[8];
    const float* Wo     = (const float*)d_in[9];
    const float* bo     = (const float*)d_in[10];
    float* out = (float*)d_out;

    unsigned short* w16   = (unsigned short*)d_ws;
    unsigned short* Xb    = w16;                                  // 2MB
    unsigned short* WqkvT = Xb    + (size_t)1024 * 1024;          // 18.9MB
    unsigned short* QKVb  = WqkvT + (size_t)QKV_N * 1024;         // 18.9MB
    unsigned short* WoT   = QKVb  + (size_t)1024 * QKV_N;         // 2MB
    unsigned short* ctxb  = WoT   + (size_t)1024 * 1024;          // 8MB
    unsigned short* avgb  = ctxb  + (size_t)64 * 1024 * 64;       // 2MB
    float* qkvb = (float*)(avgb + (size_t)1024 * 1024);           // 9216 floats
    // region reuse (sequential by stream order):
    unsigned short* VTb = WqkvT;                                  // 8MB (postproc..attn)
    float* pWo = (float*)(WqkvT + (size_t)4 * 1024 * 1024);       // 8MB (gemm_wo..reduce)

    dim3 blk(256);
    prep_kernel<<<3108, blk, 0, stream>>>(X, Wq, Wk, Wv, Wo, bq, bk, bv,
                                          Xb, WqkvT, WoT, qkvb);
    gemm_k<128, 96, 1><<<dim3(96, 8), blk, 0, stream>>>(Xb, WqkvT, qkvb, QKVb, 1024, QKV_N, 1024);
    postproc_kernel<<<1088, blk, 0, stream>>>(QKVb, VTb);
    attn_mfma<<<dim3(64, 16), blk, 0, stream>>>(QKVb, VTb, sinks, vnulls, ctxb);
    avg_kernel<<<512, blk, 0, stream>>>(ctxb, avgb);
    gemm_wo<<<dim3(16, 8, 2), blk, 0, stream>>>(avgb, WoT, pWo);
    wo_reduce<<<1024, blk, 0, stream>>>(pWo, bo, out);
}

// Round 13
// 180.904 us; speedup vs baseline: 1.5269x; 1.5269x over previous
//
#include <hip/hip_runtime.h>
#include <math.h>

#define SILU_SCALE 1.8137993642342178f   // pi/sqrt(3)
#define QKV_N 9216                       // 4096 Q | 1024 K | 4096 V
#define LN2 0.6931471805599453f
#define DNSCALE 0.18033688011112042f     // 0.125 * log2(e)

typedef __attribute__((ext_vector_type(8))) short bf16x8;
typedef __attribute__((ext_vector_type(4))) float f32x4;

#if __has_builtin(__builtin_amdgcn_exp2f)
#define EXP2(x) __builtin_amdgcn_exp2f(x)
#else
#define EXP2(x) exp2f(x)
#endif
#if __has_builtin(__builtin_amdgcn_logf)
#define LOG2(x) __builtin_amdgcn_logf(x)
#else
#define LOG2(x) __log2f(x)
#endif

__device__ __forceinline__ unsigned short f2bf(float f){
    union { float f; unsigned int i; } u; u.f = f;
    unsigned int r = u.i + 0x7FFFu + ((u.i >> 16) & 1u);   // RNE
    return (unsigned short)(r >> 16);
}
__device__ __forceinline__ float bf2f(unsigned short s){
    union { unsigned int i; float f; } u; u.i = ((unsigned int)s) << 16;
    return u.f;
}
// pack two fp32 -> [hi:lo] bf16 pair
__device__ __forceinline__ unsigned int pack_bf2(float lo, float hi){
    unsigned int i0 = __float_as_uint(lo) + 0x8000u;
    unsigned int i1 = __float_as_uint(hi) + 0x8000u;
    return __builtin_amdgcn_perm(i1, i0, 0x07060302u);
}
#if __has_builtin(__builtin_amdgcn_cvt_pk_bf16_f32)
typedef __attribute__((ext_vector_type(2))) __bf16 bfp2;
__device__ __forceinline__ unsigned int pack_bf2f(float lo, float hi){
    bfp2 t = __builtin_amdgcn_cvt_pk_bf16_f32(lo, hi);
    return __builtin_bit_cast(unsigned int, t);
}
#else
__device__ __forceinline__ unsigned int pack_bf2f(float lo, float hi){
    return pack_bf2(lo, hi);
}
#endif

// ---------------- fused prep: 4 weight transposes (64x64 tiles) + X convert + bias ----------------
__global__ __launch_bounds__(256) void prep_kernel(
    const float* __restrict__ X,
    const float* __restrict__ Wq, const float* __restrict__ Wk,
    const float* __restrict__ Wv, const float* __restrict__ Wo,
    const float* __restrict__ bq, const float* __restrict__ bk,
    const float* __restrict__ bv,
    unsigned short* __restrict__ Xb, unsigned short* __restrict__ WqkvT,
    unsigned short* __restrict__ WoT, float* __restrict__ qkvb)
{
    __shared__ float t[64][65];
    int b = blockIdx.x;
    const int tid = threadIdx.x;

    if (b >= 2560){
        if (b < 3072){   // X fp32 -> bf16, 8/thread
            int i = ((b - 2560) * 256 + tid) * 8;
            float4 a = *(const float4*)&X[i];
            float4 c = *(const float4*)&X[i + 4];
            union { unsigned short u[8]; uint4 v; } o;
            o.u[0]=f2bf(a.x); o.u[1]=f2bf(a.y); o.u[2]=f2bf(a.z); o.u[3]=f2bf(a.w);
            o.u[4]=f2bf(c.x); o.u[5]=f2bf(c.y); o.u[6]=f2bf(c.z); o.u[7]=f2bf(c.w);
            *(uint4*)&Xb[i] = o.v;
        } else {          // bias pack
            int i = (b - 3072) * 256 + tid;
            float v;
            if (i < 4096) v = bq[i];
            else if (i < 5120) v = bk[i - 4096];
            else v = bv[i - 5120];
            qkvb[i] = v;
        }
        return;
    }

    const float* W; unsigned short* Wt; int N, tiles_x;
    if (b < 1024)      { W = Wq; Wt = WqkvT;                       N = 4096; tiles_x = 64; }
    else if (b < 1280) { b -= 1024; W = Wk; Wt = WqkvT + (size_t)4096*1024; N = 1024; tiles_x = 16; }
    else if (b < 2304) { b -= 1280; W = Wv; Wt = WqkvT + (size_t)5120*1024; N = 4096; tiles_x = 64; }
    else               { b -= 2304; W = Wo; Wt = WoT;              N = 1024; tiles_x = 16; }

    const int k0 = (b / tiles_x) * 64, n0 = (b % tiles_x) * 64;
    const int lr  = tid >> 4;          // 0..15
    const int lc4 = (tid & 15) * 4;    // 0..60
    #pragma unroll
    for (int p = 0; p < 4; p++){
        int r = lr + p * 16;
        float4 v = *(const float4*)&W[(size_t)(k0 + r) * N + n0 + lc4];
        t[lc4+0][r] = v.x; t[lc4+1][r] = v.y;
        t[lc4+2][r] = v.z; t[lc4+3][r] = v.w;
    }
    __syncthreads();
    const int wr  = tid >> 3;          // 0..31
    const int wc8 = (tid & 7) * 8;     // 0..56
    #pragma unroll
    for (int p = 0; p < 2; p++){
        int r = wr + p * 32;
        union { unsigned short u[8]; uint4 v; } o;
        #pragma unroll
        for (int j = 0; j < 8; j++) o.u[j] = f2bf(t[r][wc8 + j]);
        *(uint4*)&Wt[(size_t)(n0 + r) * 1024 + k0 + wc8] = o.v;
    }
}

// ---- QKV GEMM: C[1024][9216] = Xb[1024][1024] @ WqkvT[9216][1024]^T + bias ----
// Register-prefetch pipelined with NAMED SCALAR uint4s (arrays failed SROA -> scratch
// spill in r11/r12: 195-341MB WRITE_SIZE). Mirrors attn_mfma's proven pattern.
// Slot rows differ by 32 (=0 mod 8) so the xor-swizzled chunk cc is slot-uniform.
__global__ __launch_bounds__(256) void gemm_qkv(
    const unsigned short* __restrict__ A,
    const unsigned short* __restrict__ Bt,
    const float* __restrict__ bias,
    unsigned short* __restrict__ C)
{
    constexpr int MT = 4, NT = 3;
    __shared__ unsigned short As[128 * 64];
    __shared__ unsigned short Bs[96 * 64];
    const int tid  = threadIdx.x;
    const int wave = tid >> 6;
    const int lane = tid & 63;
    const int l15  = lane & 15;
    const int quad = lane >> 4;
    const int m0 = blockIdx.y * 128;
    const int n0 = blockIdx.x * 96;
    const int wm = (wave >> 1) * 64;
    const int wn = (wave & 1) * 48;

    const int r0 = tid >> 3;                 // staging row base 0..31
    const int cc = (tid & 7) ^ (r0 & 7);     // xor-swizzled chunk (slot-uniform)
    const unsigned short* Ap = A  + (size_t)(m0 + r0) * 1024 + cc * 8;
    const unsigned short* Bp = Bt + (size_t)(n0 + r0) * 1024 + cc * 8;
    constexpr size_t STR = (size_t)32 * 1024;

    f32x4 acc[MT][NT];
    #pragma unroll
    for (int i = 0; i < MT; i++)
        #pragma unroll
        for (int j = 0; j < NT; j++)
            acc[i][j] = (f32x4){0.f, 0.f, 0.f, 0.f};

    uint4 a0 = *(const uint4*)(Ap);
    uint4 a1 = *(const uint4*)(Ap + STR);
    uint4 a2 = *(const uint4*)(Ap + 2 * STR);
    uint4 a3 = *(const uint4*)(Ap + 3 * STR);
    uint4 b0 = *(const uint4*)(Bp);
    uint4 b1 = *(const uint4*)(Bp + STR);
    uint4 b2 = *(const uint4*)(Bp + 2 * STR);

    for (int k0 = 0; k0 < 1024; k0 += 64){
        __syncthreads();                 // previous tile's LDS reads done
        *(uint4*)&As[(size_t)(0 * 256 + tid) * 8] = a0;
        *(uint4*)&As[(size_t)(1 * 256 + tid) * 8] = a1;
        *(uint4*)&As[(size_t)(2 * 256 + tid) * 8] = a2;
        *(uint4*)&As[(size_t)(3 * 256 + tid) * 8] = a3;
        *(uint4*)&Bs[(size_t)(0 * 256 + tid) * 8] = b0;
        *(uint4*)&Bs[(size_t)(1 * 256 + tid) * 8] = b1;
        *(uint4*)&Bs[(size_t)(2 * 256 + tid) * 8] = b2;

        if (k0 + 64 < 1024){             // prefetch next K-tile under this tile's MFMA
            const unsigned short* An = Ap + k0 + 64;
            const unsigned short* Bn = Bp + k0 + 64;
            a0 = *(const uint4*)(An);
            a1 = *(const uint4*)(An + STR);
            a2 = *(const uint4*)(An + 2 * STR);
            a3 = *(const uint4*)(An + 3 * STR);
            b0 = *(const uint4*)(Bn);
            b1 = *(const uint4*)(Bn + STR);
            b2 = *(const uint4*)(Bn + 2 * STR);
        }
        __syncthreads();                 // staging visible

        #pragma unroll
        for (int ks = 0; ks < 2; ks++){
            bf16x8 af[MT], bfr[NT];
            #pragma unroll
            for (int i = 0; i < MT; i++){
                int row = wm + i * 16 + l15;
                int phys = (ks * 4 + quad) ^ (row & 7);
                af[i] = *(const bf16x8*)&As[row * 64 + phys * 8];
            }
            #pragma unroll
            for (int j = 0; j < NT; j++){
                int row = wn + j * 16 + l15;
                int phys = (ks * 4 + quad) ^ (row & 7);
                bfr[j] = *(const bf16x8*)&Bs[row * 64 + phys * 8];
            }
            #pragma unroll
            for (int i = 0; i < MT; i++)
                #pragma unroll
                for (int j = 0; j < NT; j++)
                    acc[i][j] = __builtin_amdgcn_mfma_f32_16x16x32_bf16(af[i], bfr[j], acc[i][j], 0, 0, 0);
        }
    }
    #pragma unroll
    for (int i = 0; i < MT; i++){
        #pragma unroll
        for (int j = 0; j < NT; j++){
            int col = n0 + wn + j * 16 + l15;
            float bv = bias[col];
            #pragma unroll
            for (int r = 0; r < 4; r++){
                int row = m0 + wm + i * 16 + quad * 4 + r;
                C[(size_t)row * QKV_N + col] = f2bf(acc[i][j][r] + bv);
            }
        }
    }
}

// ---------------- Wo GEMM, split-K=2, scalar register-prefetch ----------------
__global__ __launch_bounds__(256) void gemm_wo(
    const unsigned short* __restrict__ A,    // avgb [1024][1024] bf16
    const unsigned short* __restrict__ Bt,   // WoT  [1024][1024] bf16
    float* __restrict__ P)                   // [2][1024][1024] fp32 partials
{
    constexpr int MT = 4, NT = 2;
    __shared__ unsigned short As[128 * 64];
    __shared__ unsigned short Bs[64 * 64];
    const int tid  = threadIdx.x;
    const int wave = tid >> 6;
    const int lane = tid & 63;
    const int l15  = lane & 15;
    const int quad = lane >> 4;
    const int m0 = blockIdx.y * 128;
    const int n0 = blockIdx.x * 64;
    const int kz = blockIdx.z;
    const int wm = (wave >> 1) * 64;
    const int wn = (wave & 1) * 32;

    const int r0 = tid >> 3;
    const int cc = (tid & 7) ^ (r0 & 7);
    const int kbeg = kz * 512;
    const unsigned short* Ap = A  + (size_t)(m0 + r0) * 1024 + kbeg + cc * 8;
    const unsigned short* Bp = Bt + (size_t)(n0 + r0) * 1024 + kbeg + cc * 8;
    constexpr size_t STR = (size_t)32 * 1024;

    f32x4 acc[MT][NT];
    #pragma unroll
    for (int i = 0; i < MT; i++)
        #pragma unroll
        for (int j = 0; j < NT; j++)
            acc[i][j] = (f32x4){0.f, 0.f, 0.f, 0.f};

    uint4 a0 = *(const uint4*)(Ap);
    uint4 a1 = *(const uint4*)(Ap + STR);
    uint4 a2 = *(const uint4*)(Ap + 2 * STR);
    uint4 a3 = *(const uint4*)(Ap + 3 * STR);
    uint4 b0 = *(const uint4*)(Bp);
    uint4 b1 = *(const uint4*)(Bp + STR);

    for (int kk = 0; kk < 512; kk += 64){
        __syncthreads();
        *(uint4*)&As[(size_t)(0 * 256 + tid) * 8] = a0;
        *(uint4*)&As[(size_t)(1 * 256 + tid) * 8] = a1;
        *(uint4*)&As[(size_t)(2 * 256 + tid) * 8] = a2;
        *(uint4*)&As[(size_t)(3 * 256 + tid) * 8] = a3;
        *(uint4*)&Bs[(size_t)(0 * 256 + tid) * 8] = b0;
        *(uint4*)&Bs[(size_t)(1 * 256 + tid) * 8] = b1;

        if (kk + 64 < 512){
            const unsigned short* An = Ap + kk + 64;
            const unsigned short* Bn = Bp + kk + 64;
            a0 = *(const uint4*)(An);
            a1 = *(const uint4*)(An + STR);
            a2 = *(const uint4*)(An + 2 * STR);
            a3 = *(const uint4*)(An + 3 * STR);
            b0 = *(const uint4*)(Bn);
            b1 = *(const uint4*)(Bn + STR);
        }
        __syncthreads();

        #pragma unroll
        for (int ks = 0; ks < 2; ks++){
            bf16x8 af[MT], bfr[NT];
            #pragma unroll
            for (int i = 0; i < MT; i++){
                int row = wm + i * 16 + l15;
                int phys = (ks * 4 + quad) ^ (row & 7);
                af[i] = *(const bf16x8*)&As[row * 64 + phys * 8];
            }
            #pragma unroll
            for (int j = 0; j < NT; j++){
                int row = wn + j * 16 + l15;
                int phys = (ks * 4 + quad) ^ (row & 7);
                bfr[j] = *(const bf16x8*)&Bs[row * 64 + phys * 8];
            }
            #pragma unroll
            for (int i = 0; i < MT; i++)
                #pragma unroll
                for (int j = 0; j < NT; j++)
                    acc[i][j] = __builtin_amdgcn_mfma_f32_16x16x32_bf16(af[i], bfr[j], acc[i][j], 0, 0, 0);
        }
    }
    float* Pz = P + (size_t)kz * 1024 * 1024;
    #pragma unroll
    for (int i = 0; i < MT; i++){
        #pragma unroll
        for (int j = 0; j < NT; j++){
            int col = n0 + wn + j * 16 + l15;
            #pragma unroll
            for (int r = 0; r < 4; r++){
                int row = m0 + wm + i * 16 + quad * 4 + r;
                Pz[(size_t)row * 1024 + col] = acc[i][j][r];
            }
        }
    }
}

// out = P[0] + P[1] + bias  (fp32, 4/thread)
__global__ void wo_reduce(const float* __restrict__ P, const float* __restrict__ bo,
                          float* __restrict__ out)
{
    int i = (blockIdx.x * 256 + threadIdx.x) * 4;   // 1M floats
    float4 a = *(const float4*)&P[i];
    float4 b = *(const float4*)&P[1024 * 1024 + i];
    float4 c = *(const float4*)&bo[i & 1023];
    float4 o;
    o.x = a.x + b.x + c.x; o.y = a.y + b.y + c.y;
    o.z = a.z + b.z + c.z; o.w = a.w + b.w + c.w;
    *(float4*)&out[i] = o;
}

// ---------------- postproc: K-rope + fold 0.125*log2e/||k|| INTO K; V pre-transpose ----------------
__global__ __launch_bounds__(256) void postproc_kernel(
    unsigned short* __restrict__ qkv, unsigned short* __restrict__ VT)
{
    int b = blockIdx.x;
    const int tid = threadIdx.x;
    if (b < 64){
        int idx = b * 256 + tid;     // 16384: (t, kh 0..15)
        int t = idx >> 4, h = idx & 15;
        unsigned short* p = qkv + (size_t)t * QKV_N + 4096 + h * 64;
        uint4 raw[8];
        #pragma unroll
        for (int i = 0; i < 8; i++) raw[i] = *(const uint4*)(p + i * 8);
        const unsigned short* rp = (const unsigned short*)raw;
        float x[64];
        #pragma unroll
        for (int i = 0; i < 64; i++) x[i] = bf2f(rp[i]);
        float ra[32], rb[32];
        float ss = 0.f;
        #pragma unroll
        for (int d = 0; d < 32; d++){
            float inv = EXP2(-(float)d * 0.4152410118609203f);   // log2(1e4)/32
            float s, c; __sincosf((float)t * inv, &s, &c);
            float x1 = x[2*d], x2 = x[2*d+1];
            float a = x1 * c - x2 * s;
            float bb = x1 * s + x2 * c;
            ss = fmaf(a, a, fmaf(bb, bb, ss));
            ra[d] = a; rb[d] = bb;
        }
        float scale = DNSCALE * rsqrtf(fmaxf(ss, 1e-6f));
        unsigned short o[64];
        #pragma unroll
        for (int d = 0; d < 32; d++){
            o[d]      = f2bf(ra[d] * scale);
            o[d + 32] = f2bf(rb[d] * scale);
        }
        #pragma unroll
        for (int i = 0; i < 8; i++) *(uint4*)(p + i * 8) = ((const uint4*)o)[i];
        return;
    }
    // V transpose: tile (h, tb): V[s0..+64][h*64..+64] -> VT[h][d][s0..+64]
    b -= 64;
    const int h = b >> 4, s0 = (b & 15) * 64;
    __shared__ unsigned short tile[64 * 64];
    const unsigned short* V = qkv + 5120;
    const int pr = tid >> 3, cch = tid & 7;
    uint4 g0 = *(const uint4*)&V[(size_t)(s0 + 2 * pr)     * QKV_N + h * 64 + cch * 8];
    uint4 g1 = *(const uint4*)&V[(size_t)(s0 + 2 * pr + 1) * QKV_N + h * 64 + cch * 8];
    const unsigned short* p0 = (const unsigned short*)&g0;
    const unsigned short* p1 = (const unsigned short*)&g1;
    #pragma unroll
    for (int j = 0; j < 8; j++){
        int d = cch * 8 + j;
        int physc = (pr >> 2) ^ ((d ^ (d >> 3)) & 7);
        unsigned int val = (unsigned int)p0[j] | ((unsigned int)p1[j] << 16);
        ((unsigned int*)tile)[d * 32 + physc * 4 + (pr & 3)] = val;
    }
    __syncthreads();
    #pragma unroll
    for (int i = 0; i < 2; i++){
        int slot = tid + i * 256;
        int d = slot >> 3, c = slot & 7;
        int phys = c ^ ((d ^ (d >> 3)) & 7);
        uint4 v = *(const uint4*)&tile[d * 64 + phys * 8];
        *(uint4*)&VT[((size_t)h * 64 + d) * 1024 + s0 + c * 8] = v;
    }
}

// ---------------- fused attention (pipelined; K pre-scaled; den via MFMA-ones) ----------------
// grid (h 0..63, qy 0..15), qt = 15 - qy. 256 thr = 4 waves; wave w owns q rows [w*16,+16).
// P stores w/ln2; epilogue applies LN2 to num and den.
__global__ __launch_bounds__(256) void attn_mfma(
    const unsigned short* __restrict__ qkv,
    const unsigned short* __restrict__ VT,   // [64][64][1024]
    const float* __restrict__ sinks, const float* __restrict__ vnulls,
    unsigned short* __restrict__ ctx)        // [64][1024][64] bf16
{
    __shared__ unsigned short ks[64 * 64];   // [s][chunk ^ (s&7)]
    __shared__ unsigned short vt[64 * 64];   // [d][chunk ^ (d&7)]
    __shared__ unsigned short ws[64][72];    // P [q][s]

    const int tid  = threadIdx.x;
    const int wave = tid >> 6;          // 0..3
    const int lane = tid & 63;
    const int l15  = lane & 15;
    const int quad = lane >> 4;
    const int h  = blockIdx.x;
    const int kh = h & 15;
    const int qt = 15 - blockIdx.y;
    const int t0 = qt << 6;

    const unsigned short* Q  = qkv;
    const unsigned short* Kp = qkv + 4096;
    const unsigned short* Vh = VT + (size_t)h * 64 * 1024;

    const int srow0 = tid >> 3,         sphy0 = tid & 7;
    const int srow1 = (tid + 256) >> 3, sphy1 = tid & 7;
    const int sc0 = sphy0 ^ (srow0 & 7);
    const int sc1 = sphy1 ^ (srow1 & 7);

    // Q fragment with fused RoPE (Q in global is un-roped).
    bf16x8 qf0, qf1;
    {
        const int t = t0 + wave * 16 + l15;
        const unsigned short* qp = Q + (size_t)t * QKV_N + h * 64 + quad * 16;
        uint4 r0 = *(const uint4*)qp;
        uint4 r1 = *(const uint4*)(qp + 8);
        unsigned short e[16];
        *(uint4*)&e[0] = r0; *(uint4*)&e[8] = r1;
        unsigned short o0[8], o1[8];
        #pragma unroll
        for (int j = 0; j < 8; j++){
            int dp = quad * 8 + j;
            float inv = EXP2(-(float)dp * 0.4152410118609203f);
            float s, c; __sincosf((float)t * inv, &s, &c);
            float x1 = bf2f(e[2*j]), x2 = bf2f(e[2*j+1]);
            o0[j] = f2bf(x1 * c - x2 * s);
            o1[j] = f2bf(x1 * s + x2 * c);
        }
        qf0 = *(const bf16x8*)o0;
        qf1 = *(const bf16x8*)o1;
    }

    // ones fragment for the den row-sum MFMA
    bf16x8 ones;
    {
        union { unsigned short u[8]; bf16x8 v; } o;
        #pragma unroll
        for (int j = 0; j < 8; j++) o.u[j] = 0x3F80;   // bf16 1.0
        ones = o.v;
    }

    f32x4 acc_o[4];
    #pragma unroll
    for (int i = 0; i < 4; i++) acc_o[i] = (f32x4){0.f, 0.f, 0.f, 0.f};
    f32x4 acc_den = (f32x4){0.f, 0.f, 0.f, 0.f};   // den[q=quad*4+r]
    const int q_glob = t0 + wave * 16 + l15;

    uint4 kr0, kr1, vr0, vr1;
    // prefetch st = 0
    {
        kr0 = *(const uint4*)&Kp[(size_t)srow0 * QKV_N + kh * 64 + sc0 * 8];
        kr1 = *(const uint4*)&Kp[(size_t)srow1 * QKV_N + kh * 64 + sc1 * 8];
        vr0 = *(const uint4*)&Vh[(size_t)srow0 * 1024 + sc0 * 8];
        vr1 = *(const uint4*)&Vh[(size_t)srow1 * 1024 + sc1 * 8];
    }

    for (int st = 0; st <= qt; st++){
        const int s0 = st << 6;
        __syncthreads();                // previous iteration's LDS reads done

        *(uint4*)&ks[(size_t)tid * 8]         = kr0;
        *(uint4*)&ks[(size_t)(tid + 256) * 8] = kr1;
        *(uint4*)&vt[(size_t)tid * 8]         = vr0;
        *(uint4*)&vt[(size_t)(tid + 256) * 8] = vr1;

        if (st < qt){                   // prefetch next (latency hidden)
            const int sn = (st + 1) << 6;
            kr0 = *(const uint4*)&Kp[(size_t)(sn + srow0) * QKV_N + kh * 64 + sc0 * 8];
            kr1 = *(const uint4*)&Kp[(size_t)(sn + srow1) * QKV_N + kh * 64 + sc1 * 8];
            vr0 = *(const uint4*)&Vh[(size_t)srow0 * 1024 + sn + sc0 * 8];
            vr1 = *(const uint4*)&Vh[(size_t)srow1 * 1024 + sn + sc1 * 8];
        }
        __syncthreads();                // staging visible

        const bool diag = (st == qt);

        // S^T: mfma(kf, qf) -> lane owns 4 consecutive s (quad*4+r) for q = l15.
        // K is pre-scaled: y = sc directly (in log2 space). P' = w/ln2.
        #pragma unroll
        for (int nt = 0; nt < 4; nt++){
            const int sbase = nt * 16 + quad * 4;
            uint2* wp = (uint2*)&ws[wave * 16 + l15][sbase];
            if (diag && nt > wave){ *wp = (uint2){0u, 0u}; continue; }

            f32x4 sc = (f32x4){0.f, 0.f, 0.f, 0.f};
            {
                int srow = nt * 16 + l15;
                int ph0 = quad ^ (srow & 7);
                int ph1 = (4 + quad) ^ (srow & 7);
                bf16x8 kf0 = *(const bf16x8*)&ks[srow * 64 + ph0 * 8];
                bf16x8 kf1 = *(const bf16x8*)&ks[srow * 64 + ph1 * 8];
                sc = __builtin_amdgcn_mfma_f32_16x16x32_bf16(kf0, qf0, sc, 0, 0, 0);
                sc = __builtin_amdgcn_mfma_f32_16x16x32_bf16(kf1, qf1, sc, 0, 0, 0);
            }
            float w4[4];
            if (!diag){                 // fast path: no masking
                #pragma unroll
                for (int r = 0; r < 4; r++){
                    float y = sc[r];
                    float p = EXP2(-fabsf(y));
                    float u = fmaxf(y, 0.f) + LOG2(1.f + p);      // softplus * log2(e)
                    float e3 = EXP2(-SILU_SCALE * u);
                    w4[r] = __fdividef(u, 1.f + e3);              // w / ln2
                }
            } else {
                #pragma unroll
                for (int r = 0; r < 4; r++){
                    float y = sc[r];
                    float p = EXP2(-fabsf(y));
                    float u = fmaxf(y, 0.f) + LOG2(1.f + p);
                    float e3 = EXP2(-SILU_SCALE * u);
                    float wv = __fdividef(u, 1.f + e3);
                    w4[r] = (s0 + sbase + r <= q_glob) ? wv : 0.f;
                }
            }
            uint2 pk;
            pk.x = pack_bf2f(w4[0], w4[1]);
            pk.y = pack_bf2f(w4[2], w4[3]);
            *wp = pk;
        }

        // PV + den row-sum (wave-private ws rows)
        {
            const int prow = wave * 16 + l15;
            bf16x8 pf0 = *(const bf16x8*)&ws[prow][quad * 8];
            bf16x8 pf1 = *(const bf16x8*)&ws[prow][32 + quad * 8];
            const bool skip_hi = diag && (wave <= 1);   // s>=32 all masked (zeros)
            #pragma unroll
            for (int dt = 0; dt < 4; dt++){
                int d = dt * 16 + l15;
                int sw = d & 7;
                bf16x8 vf0 = *(const bf16x8*)&vt[d * 64 + (quad ^ sw) * 8];
                acc_o[dt] = __builtin_amdgcn_mfma_f32_16x16x32_bf16(pf0, vf0, acc_o[dt], 0, 0, 0);
                if (!skip_hi){
                    bf16x8 vf1 = *(const bf16x8*)&vt[d * 64 + ((4 + quad) ^ sw) * 8];
                    acc_o[dt] = __builtin_amdgcn_mfma_f32_16x16x32_bf16(pf1, vf1, acc_o[dt], 0, 0, 0);
                }
            }
            acc_den = __builtin_amdgcn_mfma_f32_16x16x32_bf16(pf0, ones, acc_den, 0, 0, 0);
            if (!skip_hi)
                acc_den = __builtin_amdgcn_mfma_f32_16x16x32_bf16(pf1, ones, acc_den, 0, 0, 0);
        }
    }

    // epilogue: den[q=quad*4+r] = acc_den[r]; apply LN2 scale to num and den
    float sinkv = tanhf(sinks[h]) + 1e-6f;
    #pragma unroll
    for (int r = 0; r < 4; r++){
        int qg = t0 + wave * 16 + quad * 4 + r;
        float alpha = __fdividef(1.f, LN2 * acc_den[r] + sinkv + 1e-6f);
        #pragma unroll
        for (int dt = 0; dt < 4; dt++){
            int d = dt * 16 + l15;
            float o = (LN2 * acc_o[dt][r] + sinkv * vnulls[h * 64 + d]) * alpha;
            ctx[((size_t)h * 1024 + qg) * 64 + d] = f2bf(o);
        }
    }
}

// avg over 4 branches -> bf16 [t][nh*64+d], 8 elems/thread
__global__ void avg_kernel(const unsigned short* __restrict__ ctx, unsigned short* __restrict__ avg)
{
    int i8 = (blockIdx.x * 256 + threadIdx.x) * 8;   // 1M elements
    int t = i8 >> 10, c = i8 & 1023;
    int nh = c >> 6, d = c & 63;
    float s[8] = {};
    #pragma unroll
    for (int br = 0; br < 4; br++){
        uint4 v = *(const uint4*)&ctx[((size_t)(br * 16 + nh) * 1024 + t) * 64 + d];
        const unsigned short* p = (const unsigned short*)&v;
        #pragma unroll
        for (int j = 0; j < 8; j++) s[j] += bf2f(p[j]);
    }
    union { unsigned short u[8]; uint4 v; } o;
    #pragma unroll
    for (int j = 0; j < 8; j++) o.u[j] = f2bf(0.25f * s[j]);
    *(uint4*)&avg[i8] = o.v;
}

extern "C" void kernel_launch(void* const* d_in, const int* in_sizes, int n_in,
                              void* d_out, int out_size, void* d_ws, size_t ws_size,
                              hipStream_t stream)
{
    (void)in_sizes; (void)n_in; (void)out_size; (void)ws_size;
    const float* X      = (const float*)d_in[0];
    const float* Wq     = (const float*)d_in[1];
    const float* bq     = (const float*)d_in[2];
    const float* Wk     = (const float*)d_in[3];
    const float* bk     = (const float*)d_in[4];
    const float* Wv     = (const float*)d_in[5];
    const float* bv     = (const float*)d_in[6];
    const float* sinks  = (const float*)d_in[7];
    const float* vnulls = (const float*)d_in[8];
    const float* Wo     = (const float*)d_in[9];
    const float* bo     = (const float*)d_in[10];
    float* out = (float*)d_out;

    unsigned short* w16   = (unsigned short*)d_ws;
    unsigned short* Xb    = w16;                                  // 2MB
    unsigned short* WqkvT = Xb    + (size_t)1024 * 1024;          // 18.9MB
    unsigned short* QKVb  = WqkvT + (size_t)QKV_N * 1024;         // 18.9MB
    unsigned short* WoT   = QKVb  + (size_t)1024 * QKV_N;         // 2MB
    unsigned short* ctxb  = WoT   + (size_t)1024 * 1024;          // 8MB
    unsigned short* avgb  = ctxb  + (size_t)64 * 1024 * 64;       // 2MB
    float* qkvb = (float*)(avgb + (size_t)1024 * 1024);           // 9216 floats
    // region reuse (sequential by stream order):
    unsigned short* VTb = WqkvT;                                  // 8MB (postproc..attn)
    float* pWo = (float*)(WqkvT + (size_t)4 * 1024 * 1024);       // 8MB (gemm_wo..reduce)

    dim3 blk(256);
    prep_kernel<<<3108, blk, 0, stream>>>(X, Wq, Wk, Wv, Wo, bq, bk, bv,
                                          Xb, WqkvT, WoT, qkvb);
    gemm_qkv<<<dim3(96, 8), blk, 0, stream>>>(Xb, WqkvT, qkvb, QKVb);
    postproc_kernel<<<1088, blk, 0, stream>>>(QKVb, VTb);
    attn_mfma<<<dim3(64, 16), blk, 0, stream>>>(QKVb, VTb, sinks, vnulls, ctxb);
    avg_kernel<<<512, blk, 0, stream>>>(ctxb, avgb);
    gemm_wo<<<dim3(16, 8, 2), blk, 0, stream>>>(avgb, WoT, pWo);
    wo_reduce<<<1024, blk, 0, stream>>>(pWo, bo, out);
}